// Round 2
// baseline (154.191 us; speedup 1.0000x reference)
//
#include <hip/hip_runtime.h>
#include <hip/hip_bf16.h>

// Problem constants
#define B_  4096
#define T_  80
#define E_  100
#define U_  64
#define G_  256    // 4*U
#define V_  10000

#define S_H  72    // hbuf row stride (bf16 elems), 144B rows; 16B-cluster map (9n+kg)%8 is uniform -> conflict-free
#define TS   81    // token LDS row stride (ints); 81%32=17 odd -> 16 rows spread over 16 banks (80 gave 2 banks, 8-way)

typedef __attribute__((ext_vector_type(8))) __bf16 bf16x8;
typedef __attribute__((ext_vector_type(4))) __bf16 bf16x4;
typedef __attribute__((ext_vector_type(4))) float  floatx4;

__device__ __forceinline__ float sigmoidf_(float x) {
    return __builtin_amdgcn_rcpf(1.f + __expf(-x));
}

__device__ __forceinline__ float tanhf_(float x) {
    // 1 - 2/(e^{2x}+1): monotone, saturates correctly, no NaN
    return fmaf(-2.f, __builtin_amdgcn_rcpf(__expf(2.f * x) + 1.f), 1.f);
}

// Block-wide barrier WITHOUT the vmcnt(0) drain __syncthreads() forces.
// Only LDS traffic (h writes) must be visible across waves per step; the
// emb gather loads are thread-private VGPR fills tracked by the compiler's
// own counted s_waitcnt vmcnt(N) at first use.
__device__ __forceinline__ void block_sync_lgkm() {
    asm volatile("s_waitcnt lgkmcnt(0)\n\ts_barrier" ::: "memory");
}

__device__ __forceinline__ bf16x8 cvt8(const float4& a, const float4& b) {
    bf16x8 r;
    r[0] = (__bf16)a.x; r[1] = (__bf16)a.y; r[2] = (__bf16)a.z; r[3] = (__bf16)a.w;
    r[4] = (__bf16)b.x; r[5] = (__bf16)b.y; r[6] = (__bf16)b.z; r[7] = (__bf16)b.w;
    return r;
}

// ---------------------------------------------------------------------------
// Single fused kernel. Recurrence via TRANSPOSED MFMA: z^T = k1^T x^T + r1^T h^T + b.
// 256 blocks x 256 threads (4 waves). Block = 16 batch rows; wave w owns
// units [w*16, w*16+16) -> 4 gate-col tiles. The x-projection (dead-reckonable
// from tokens) is computed ONE STEP AHEAD on the MFMA pipe, overlapping the
// gate VALU of the current step (separate pipes). emb (4 MB) is L2-resident,
// so the per-step gather is cheap and fully hidden by the 1-step staging
// pipeline. This replaces the embk precompute kernel (10.2 MB table, L3-latency
// gathers, extra launch + serialization) entirely.
//
// Accumulation order (bias -> 4 E-chunk MFMAs -> 2 h-MFMAs, C-chained) is
// arithmetically identical to the previous embk+lstm split.
// ---------------------------------------------------------------------------
__global__ __launch_bounds__(256, 1) void lstm_kernel(const int*   __restrict__ tokens,
                                                      const float* __restrict__ emb,
                                                      const float* __restrict__ k1,
                                                      const float* __restrict__ r1,
                                                      const float* __restrict__ b1,
                                                      const float* __restrict__ Wd,
                                                      const float* __restrict__ bd,
                                                      float* __restrict__ out) {
    __shared__ int    tokLDS[16 * TS];       // 5.18 KB
    __shared__ __bf16 hbuf[2][16 * S_H];     // 4.6 KB

    const int tid  = threadIdx.x;
    const int lane = tid & 63;
    const int w    = tid >> 6;               // unit block [w*16, w*16+16)
    const int n    = lane & 15;              // batch row (N-operand of MFMA)
    const int kg   = lane >> 4;              // 0..3
    const int bb   = blockIdx.x * 16;

    for (int i = tid; i < 16 * T_; i += 256)
        tokLDS[(i / T_) * TS + (i % T_)] = tokens[bb * T_ + i];
    for (int i = tid; i < 2 * 16 * S_H; i += 256) (&hbuf[0][0])[i] = (__bf16)0.f;

    // A-fragments = r1^T (static): tile ct covers gate-cols ct*64 + w*16 + m,
    // A[m][k] = r1[k][ct*64 + w*16 + m]; lane holds m = n, k = kc*32 + kg*8 + jj
    bf16x8 afr[4][2];
#pragma unroll
    for (int ct = 0; ct < 4; ++ct)
#pragma unroll
        for (int kc = 0; kc < 2; ++kc) {
            bf16x8 s;
#pragma unroll
            for (int jj = 0; jj < 8; ++jj)
                s[jj] = (__bf16)r1[(kc * 32 + kg * 8 + jj) * G_ + ct * 64 + w * 16 + n];
            afr[ct][kc] = s;
        }

    // A-fragments = k1^T (static), K padded 100 -> 128 with zeros
    bf16x8 kfr[4][4];
#pragma unroll
    for (int ct = 0; ct < 4; ++ct)
#pragma unroll
        for (int kc = 0; kc < 4; ++kc) {
            bf16x8 s;
#pragma unroll
            for (int jj = 0; jj < 8; ++jj) {
                int k = kc * 32 + kg * 8 + jj;
                s[jj] = (k < E_) ? (__bf16)k1[k * G_ + ct * 64 + w * 16 + n]
                                 : (__bf16)0.f;
            }
            kfr[ct][kc] = s;
        }

    // bias in C layout: row of C = gate col = ct*64 + w*16 + kg*4 + r
    floatx4 bias[4];
#pragma unroll
    for (int ct = 0; ct < 4; ++ct)
#pragma unroll
        for (int r = 0; r < 4; ++r)
            bias[ct][r] = b1[ct * 64 + w * 16 + kg * 4 + r];

    // cell state: 4 cells/lane: (row n, unit w*16 + 4*kg + r)
    float c[4] = {0.f, 0.f, 0.f, 0.f};

    __syncthreads();                         // tokens + zeroed hbuf visible (once)

    const int trow = n * TS;

    // ---- emb staging: lane (n,kg) supplies B[k][n] = emb[tok_n][k],
    //      k = kc*32 + kg*8 + jj. 7 x dwordx4 per lane (kc=3 only kg==0 valid).
    auto ldstage = [&](int tk, float4* st) {
        const float* base = emb + (long)tk * E_;
#pragma unroll
        for (int kc = 0; kc < 3; ++kc) {
            st[kc * 2]     = *(const float4*)(base + kc * 32 + kg * 8);
            st[kc * 2 + 1] = *(const float4*)(base + kc * 32 + kg * 8 + 4);
        }
        st[6] = *(const float4*)(base + 96);  // uniform issue; masked in xbuild
    };

    // ---- x-projection: xo[ct] = b + k1^T x^T  (16 MFMA, off critical path)
    auto xbuild = [&](const float4* st, floatx4* xo) {
        bf16x8 x0 = cvt8(st[0], st[1]);
        bf16x8 x1 = cvt8(st[2], st[3]);
        bf16x8 x2 = cvt8(st[4], st[5]);
        float4 e3 = st[6];
        if (kg) { e3.x = 0.f; e3.y = 0.f; e3.z = 0.f; e3.w = 0.f; }
        bf16x8 x3;
        x3[0] = (__bf16)e3.x; x3[1] = (__bf16)e3.y;
        x3[2] = (__bf16)e3.z; x3[3] = (__bf16)e3.w;
        x3[4] = (__bf16)0.f;  x3[5] = (__bf16)0.f;
        x3[6] = (__bf16)0.f;  x3[7] = (__bf16)0.f;
#pragma unroll
        for (int ct = 0; ct < 4; ++ct) {
            floatx4 a = bias[ct];
            a = __builtin_amdgcn_mfma_f32_16x16x32_bf16(kfr[ct][0], x0, a, 0, 0, 0);
            a = __builtin_amdgcn_mfma_f32_16x16x32_bf16(kfr[ct][1], x1, a, 0, 0, 0);
            a = __builtin_amdgcn_mfma_f32_16x16x32_bf16(kfr[ct][2], x2, a, 0, 0, 0);
            a = __builtin_amdgcn_mfma_f32_16x16x32_bf16(kfr[ct][3], x3, a, 0, 0, 0);
            xo[ct] = a;
        }
    };

    // ---- prologue: fill the 2-deep x pipeline
    float4  stA[7], stB[7];
    floatx4 xaccA[4], xaccB[4];

    ldstage(tokLDS[trow + 0], stA);          // token 0
    xbuild(stA, xaccA);                      // z_x(t=0)
    ldstage(tokLDS[trow + 1], stB);          // token 1 -> consumed in step 0
    int tkA = tokLDS[trow + 2];              // loads issued at even steps (t+2)
    int tkB = tokLDS[trow + 3];              // loads issued at odd steps  (t+2)

    auto step = [&](int t, const __bf16* hbR, __bf16* hbW,
                    floatx4* xuse, floatx4* xbld,
                    float4* stuse, float4* stbld, int& tkpf) {
        // B-fragments = h^T_{t-1}
        bf16x8 b0  = *(const bf16x8*)(hbR + n * S_H + kg * 8);
        bf16x8 b1v = *(const bf16x8*)(hbR + n * S_H + 32 + kg * 8);

        // issue emb loads for token t+2 (fire-and-forget; consumed next step)
        ldstage(tkpf, stbld);
        int tnext = t + 4; if (tnext > T_ - 1) tnext = T_ - 1;
        tkpf = tokLDS[trow + tnext];

        // z^T = z_x + r1^T h^T
        floatx4 acc[4];
#pragma unroll
        for (int ct = 0; ct < 4; ++ct) {
            floatx4 a = xuse[ct];
            a = __builtin_amdgcn_mfma_f32_16x16x32_bf16(afr[ct][0], b0,  a, 0, 0, 0);
            a = __builtin_amdgcn_mfma_f32_16x16x32_bf16(afr[ct][1], b1v, a, 0, 0, 0);
            acc[ct] = a;
        }

        // gates: 4 dense cells/lane; acc[0]=i, acc[1]=f, acc[2]=g, acc[3]=o
        bf16x4 hv;
#pragma unroll
        for (int r = 0; r < 4; ++r) {
            float zi = acc[0][r], zf = acc[1][r], zg = acc[2][r], zo = acc[3][r];
            float cn = fmaf(sigmoidf_(zf), c[r], sigmoidf_(zi) * tanhf_(zg));
            float hn = sigmoidf_(zo) * tanhf_(cn);
            c[r] = cn;
            hv[r] = (__bf16)hn;
        }
        *(bf16x4*)(hbW + n * S_H + w * 16 + kg * 4) = hv;

        // x-projection for t+1 on the MFMA pipe (overlaps gate VALU / write)
        xbuild(stuse, xbld);

        block_sync_lgkm();                   // h_t visible; loads stay in flight
    };

    for (int t = 0; t < T_; t += 2) {
        step(t,     hbuf[1], hbuf[0], xaccA, xaccB, stB, stA, tkA);
        step(t + 1, hbuf[0], hbuf[1], xaccB, xaccA, stA, stB, tkB);
    }

    // out[b] = sigmoid(h_final[b] . Wd + bd); h_79 in hbuf[1]
    if (tid < 16) {
        const __bf16* hb = hbuf[1] + tid * S_H;
        float s = bd[0];
#pragma unroll
        for (int u = 0; u < U_; ++u) s = fmaf((float)hb[u], Wd[u], s);
        out[bb + tid] = sigmoidf_(s);
    }
}

// ---------------------------------------------------------------------------
extern "C" void kernel_launch(void* const* d_in, const int* in_sizes, int n_in,
                              void* d_out, int out_size, void* d_ws, size_t ws_size,
                              hipStream_t stream) {
    const int*   tokens = (const int*)  d_in[0];
    const float* emb    = (const float*)d_in[1];
    // d_in[2..4] = k0, r0, b0 : dead in the reference (cell0 state unused)
    const float* k1     = (const float*)d_in[5];
    const float* r1     = (const float*)d_in[6];
    const float* b1     = (const float*)d_in[7];
    const float* Wd     = (const float*)d_in[8];
    const float* bd     = (const float*)d_in[9];
    float*       out    = (float*)d_out;

    lstm_kernel<<<B_ / 16, 256, 0, stream>>>(tokens, emb, k1, r1, b1, Wd, bd, out);
}